// Round 4
// baseline (153.518 us; speedup 1.0000x reference)
//
#include <hip/hip_runtime.h>

// VQ-VAE VectorQuantizer for MI355X — v5: outer-product register tiling (16x8/lane).
// inputs: d_in[0] = inputs [64, 64, 32, 32] fp32 (NCHW), d_in[1] = emb_w [512, 64] fp32
// output d_out (fp32): [loss(1), quantized NCHW (64*64*32*32), idx (65536)]
//
// Correctness note: the reference computes dist = ||x||^2 + ||e||^2 - 2 x.e in fp32,
// where ||x||^2 ~ 64 quantizes dist to a ~7.6e-6 grid; ~100/65536 points have quantized
// TIES that argmin resolves by first index. We bit-replicate that arithmetic
// (numpy pairwise-sum order for the norms, fp32 rounding sequence for dist: sequential
// fmaf over d=0..63, then fp32((sx+nk) - 2*dot)) and tie-break by smallest index.
//
// v5 rationale (measured economics from v1-v4): ds_read_b128 costs ~12cy of the CU's
// single LDS pipe REGARDLESS of address sharing (v3 uniform-broadcast and v1 shared
// reads both confirm); SMEM streaming stalls ~780cy/code (v4). So operands must be
// delivered by lane-distinct-ish wide reads amortized over a LARGE register tile:
// per wave per d-step, LDS = 3(P+Q) cy vs VALU = 2PQ cy. P=16,Q=8 -> 72 vs 256.
// At 1 wave/SIMD (acc[16][8]=128 VGPRs forces it), per-CU: LDS 4x72=288 vs VALU 256
// per SIMD -> VALU-bound (~89%+). x-tile rows use a 20-word chunk pitch so the 8
// pg-chunks' b128 reads start at banks {0,20,8,28,16,4,24,12} -> all 32 banks covered
// exactly once -> conflict-free. argmin stays per-lane (no per-point shuffles);
// final merge = 32 candidates/point in a x33-padded LDS array (conflict-free).

#define D_     64
#define HW_    1024
#define N_     65536
#define K_     512
#define M_     128    // points per block
#define NDTOT  (N_ * D_)
#define XP     160    // x-tile row pitch in words: 8 chunks * 20 (16 used + 4 pad)
#define EP     256    // e-tile row pitch: 256 codes per pass

__global__ __launch_bounds__(256, 1) void vq_fused_kernel(const float* __restrict__ inp,
                                                          const float* __restrict__ emb,
                                                          float* __restrict__ out) {
    __shared__ float ldsx[D_ * XP];     // 40 KB: x-tile [d][pg-chunk(20w)]
    __shared__ float ldse[D_ * EP];     // 64 KB: e-tile [d][k] per pass; later mv/mi
    __shared__ float ldsn[K_];          // ||e_k||^2
    __shared__ float sxs[M_];           // ||x_p||^2
    __shared__ int   fi[M_];            // final index per point
    __shared__ float psum[256];         // loss partials

    const int tid  = threadIdx.x;
    const int lane = tid & 63;
    const int w    = tid >> 6;          // wave 0..3
    const int pg   = lane & 7;          // point-group: 16 points each
    const int kg   = lane >> 3;         // code-group: 8 codes each
    const int n0   = blockIdx.x * M_;
    const int b    = n0 >> 10;
    const int hw0  = n0 & 1023;
    const float* xbase = inp + b * (D_ * HW_) + hw0;

    // ================= phase A: stage x, ||e||^2, e-pass0 (all overlapped) ==========
#pragma unroll
    for (int i = 0; i < 8; ++i) {
        int q = i * 256 + tid;          // 0..2047 = 64 d * 32 quads
        int d = q >> 5;
        int pq = q & 31;
        float4 v = *(const float4*)(xbase + d * HW_ + pq * 4);
        *(float4*)(ldsx + d * XP + (pq >> 2) * 20 + (pq & 3) * 4) = v;
    }
    // ||e_k||^2, numpy pairwise order (2 codes/thread)
#pragma unroll
    for (int c = 0; c < 2; ++c) {
        const int k = c * 256 + tid;
        const float* e = emb + k * D_;
        float el[64];
#pragma unroll
        for (int q = 0; q < 16; ++q) {
            float4 v = *(const float4*)(e + q * 4);
            el[4 * q + 0] = v.x; el[4 * q + 1] = v.y;
            el[4 * q + 2] = v.z; el[4 * q + 3] = v.w;
        }
        float r[8];
#pragma unroll
        for (int j = 0; j < 8; ++j) r[j] = __fmul_rn(el[j], el[j]);
#pragma unroll
        for (int i = 1; i < 8; ++i)
#pragma unroll
            for (int j = 0; j < 8; ++j)
                r[j] = __fadd_rn(r[j], __fmul_rn(el[i * 8 + j], el[i * 8 + j]));
        ldsn[k] = __fadd_rn(__fadd_rn(__fadd_rn(r[0], r[1]), __fadd_rn(r[2], r[3])),
                            __fadd_rn(__fadd_rn(r[4], r[5]), __fadd_rn(r[6], r[7])));
    }
    // e-tile pass 0: thread tid stages code row k=tid, transposed to [d][k]
    // (writes: lanes have consecutive k -> conflict-free)
#pragma unroll
    for (int i = 0; i < 16; ++i) {
        float4 v = *(const float4*)(emb + tid * D_ + i * 4);
        ldse[(i * 4 + 0) * EP + tid] = v.x;
        ldse[(i * 4 + 1) * EP + tid] = v.y;
        ldse[(i * 4 + 2) * EP + tid] = v.z;
        ldse[(i * 4 + 3) * EP + tid] = v.w;
    }
    __syncthreads();

    // ---- sxs[p] = ||x_p||^2, numpy pairwise order ----
    if (tid < M_) {
        const int xb2 = (tid >> 4) * 20 + (tid & 15);
        float r[8];
#pragma unroll
        for (int j = 0; j < 8; ++j) {
            float v = ldsx[j * XP + xb2];
            r[j] = __fmul_rn(v, v);
        }
#pragma unroll
        for (int i = 1; i < 8; ++i)
#pragma unroll
            for (int j = 0; j < 8; ++j) {
                float v = ldsx[(i * 8 + j) * XP + xb2];
                r[j] = __fadd_rn(r[j], __fmul_rn(v, v));
            }
        sxs[tid] = __fadd_rn(__fadd_rn(__fadd_rn(r[0], r[1]), __fadd_rn(r[2], r[3])),
                             __fadd_rn(__fadd_rn(r[4], r[5]), __fadd_rn(r[6], r[7])));
    }
    __syncthreads();

    // per-lane state
    float sxp[16];
    {
        float4 s0 = *(const float4*)(sxs + pg * 16);
        float4 s1 = *(const float4*)(sxs + pg * 16 + 4);
        float4 s2 = *(const float4*)(sxs + pg * 16 + 8);
        float4 s3 = *(const float4*)(sxs + pg * 16 + 12);
        sxp[0]=s0.x; sxp[1]=s0.y; sxp[2]=s0.z; sxp[3]=s0.w;
        sxp[4]=s1.x; sxp[5]=s1.y; sxp[6]=s1.z; sxp[7]=s1.w;
        sxp[8]=s2.x; sxp[9]=s2.y; sxp[10]=s2.z; sxp[11]=s2.w;
        sxp[12]=s3.x; sxp[13]=s3.y; sxp[14]=s3.z; sxp[15]=s3.w;
    }
    float runv[16];
    int   runi[16];
#pragma unroll
    for (int j = 0; j < 16; ++j) { runv[j] = 3.4e38f; runi[j] = 0; }

    // ================= main: 2 passes of 256 codes =================================
#pragma unroll 1
    for (int c = 0; c < 2; ++c) {
        if (c) {
            __syncthreads();            // pass-0 inner reads of ldse done
#pragma unroll
            for (int i = 0; i < 16; ++i) {
                float4 v = *(const float4*)(emb + (256 + tid) * D_ + i * 4);
                ldse[(i * 4 + 0) * EP + tid] = v.x;
                ldse[(i * 4 + 1) * EP + tid] = v.y;
                ldse[(i * 4 + 2) * EP + tid] = v.z;
                ldse[(i * 4 + 3) * EP + tid] = v.w;
            }
            __syncthreads();
        }
        float nk[8];
        {
            float4 na = *(const float4*)(ldsn + c * 256 + w * 64 + kg * 8);
            float4 nb = *(const float4*)(ldsn + c * 256 + w * 64 + kg * 8 + 4);
            nk[0]=na.x; nk[1]=na.y; nk[2]=na.z; nk[3]=na.w;
            nk[4]=nb.x; nk[5]=nb.y; nk[6]=nb.z; nk[7]=nb.w;
        }
        float acc[16][8];
#pragma unroll
        for (int j = 0; j < 16; ++j)
#pragma unroll
            for (int q = 0; q < 8; ++q) acc[j][q] = 0.f;

        const float* xcol = ldsx + pg * 20;
        const float* ecol = ldse + (w << 6) + (kg << 3);
#pragma unroll 4
        for (int d = 0; d < 64; ++d) {
            const float* xr = xcol + d * XP;
            float4 xa = *(const float4*)(xr);
            float4 xb4 = *(const float4*)(xr + 4);
            float4 xc4 = *(const float4*)(xr + 8);
            float4 xd4 = *(const float4*)(xr + 12);
            const float* er = ecol + d * EP;
            float4 ea = *(const float4*)(er);
            float4 eb = *(const float4*)(er + 4);
            float xv[16] = {xa.x, xa.y, xa.z, xa.w, xb4.x, xb4.y, xb4.z, xb4.w,
                            xc4.x, xc4.y, xc4.z, xc4.w, xd4.x, xd4.y, xd4.z, xd4.w};
            float ev[8]  = {ea.x, ea.y, ea.z, ea.w, eb.x, eb.y, eb.z, eb.w};
#pragma unroll
            for (int j = 0; j < 16; ++j)
#pragma unroll
                for (int q = 0; q < 8; ++q)
                    acc[j][q] = fmaf(xv[j], ev[q], acc[j][q]);   // exact d-order chain
        }

        // dist = fp32(fp32(sx + n_k) - 2*dot), strict < keeps first (codes ascending)
        const int kidx0 = c * 256 + w * 64 + kg * 8;
#pragma unroll
        for (int j = 0; j < 16; ++j) {
            float sx = sxp[j];
#pragma unroll
            for (int q = 0; q < 8; ++q) {
                float t = __fadd_rn(sx, nk[q]);
                float v = __fadd_rn(t, -2.0f * acc[j][q]);   // 2*dot exact
                if (v < runv[j]) { runv[j] = v; runi[j] = kidx0 + q; }
            }
        }
    }

    // ================= cross-lane argmin merge (32 candidates/point) ================
    __syncthreads();                     // inner reads of ldse done -> overlay mv/mi
    float* mv = ldse;                    // [128][33] padded: bank = (p+c)%32, 2-way
    int*   mi = (int*)(ldse + 128 * 33);
    const int col = w * 8 + kg;
#pragma unroll
    for (int j = 0; j < 16; ++j) {
        int p = pg * 16 + j;
        mv[p * 33 + col] = runv[j];
        mi[p * 33 + col] = runi[j];
    }
    __syncthreads();
    if (tid < M_) {
        float bv = 3.4e38f; int bi = 0x7fffffff;
#pragma unroll
        for (int g = 0; g < 32; ++g) {
            float v  = mv[tid * 33 + g];
            int   ii = mi[tid * 33 + g];
            if (v < bv || (v == bv && ii < bi)) { bv = v; bi = ii; }
        }
        fi[tid] = bi;
        out[1 + NDTOT + n0 + tid] = (float)bi;   // idx as float
    }
    __syncthreads();

    // ================= epilogue: quantized NCHW + loss =============================
    {
        const int p  = tid & 127;        // point
        const int dh = tid >> 7;         // 0/1 -> dims [32*dh, 32*dh+32)
        const float* er2 = emb + fi[p] * D_ + dh * 32;
        float ev2[32];
#pragma unroll
        for (int q = 0; q < 8; ++q) {
            float4 v = *(const float4*)(er2 + 4 * q);
            ev2[4 * q + 0] = v.x; ev2[4 * q + 1] = v.y;
            ev2[4 * q + 2] = v.z; ev2[4 * q + 3] = v.w;
        }
        float* ob = out + 1 + b * (D_ * HW_) + hw0 + p;
        const int xb2 = (p >> 4) * 20 + (p & 15);
        float local = 0.f;
#pragma unroll
        for (int dd = 0; dd < 32; ++dd) {
            float xv = ldsx[(dh * 32 + dd) * XP + xb2];
            float df = ev2[dd] - xv;
            local = fmaf(df, df, local);
            ob[(dh * 32 + dd) * HW_] = ev2[dd];   // coalesced per instr
        }
        psum[tid] = local;
    }
    __syncthreads();
    if (tid < 64) {
        float s = psum[tid] + psum[tid + 64] + psum[tid + 128] + psum[tid + 192];
#pragma unroll
        for (int off = 32; off > 0; off >>= 1)
            s += __shfl_down(s, off, 64);
        if (tid == 0)
            atomicAdd(out, s * (1.25f / (float)NDTOT));   // loss = 1.25*mean((q-x)^2)
    }
}

extern "C" void kernel_launch(void* const* d_in, const int* in_sizes, int n_in,
                              void* d_out, int out_size, void* d_ws, size_t ws_size,
                              hipStream_t stream) {
    const float* inp = (const float*)d_in[0];
    const float* emb = (const float*)d_in[1];
    float* out = (float*)d_out;
    (void)d_ws; (void)ws_size;

    hipMemsetAsync(d_out, 0, sizeof(float), stream);   // loss accumulator
    vq_fused_kernel<<<512, 256, 0, stream>>>(inp, emb, out);
}

// Round 5
// 132.191 us; speedup vs baseline: 1.1613x; 1.1613x over previous
//
#include <hip/hip_runtime.h>

// VQ-VAE VectorQuantizer for MI355X — v6: 16x8 outer-product tile at 2 waves/SIMD.
// inputs: d_in[0] = inputs [64, 64, 32, 32] fp32 (NCHW), d_in[1] = emb_w [512, 64] fp32
// output d_out (fp32): [loss(1), quantized NCHW (64*64*32*32), idx (65536)]
//
// Correctness note: the reference computes dist = ||x||^2 + ||e||^2 - 2 x.e in fp32,
// where ||x||^2 ~ 64 quantizes dist to a ~7.6e-6 grid; ~100/65536 points have quantized
// TIES that argmin resolves by first index. We bit-replicate that arithmetic
// (numpy pairwise-sum order for the norms, fp32 rounding sequence for dist: sequential
// fmaf over d=0..63 then fp32((sx+nk) - 2*dot); fmaf(-2,acc,t) == fadd(t,-2*acc) since
// -2*acc is exact) and tie-break by smallest index.
//
// v6 rationale: v1/v3 measured ds_read_b128 ~12cy of the single per-CU LDS pipe
// regardless of address sharing -> balance needs PQ >= 6(P+Q) per wave per d-step.
// v5 (P16xQ8 @ 1 wave/SIMD) proved tile economics but died on latency (no TLP,
// VGPR allocator gave 132 < demand). v6 keeps P=16,Q=8 but restructures the BLOCK:
// 512 threads (8 waves = 2/SIMD for TLP), M=256 points, grid=256 = exactly 1
// block/CU, 2 code-chunks of 256. Per CU per d-step: LDS 8x72=576cy vs VALU
// 2x256=512cy/SIMD -> near-balanced, wall ~31us. State trimmed to fit 2 waves/SIMD:
// acc 128 + runv/runi 32 (sxp re-read from LDS at chunk end) ~ 220 VGPR < 256.
// x-tile: 8 chunks x 36 floats (32 pts + 4 pad): bank starts {0,16,4,20,...} 2-way
// max (free), 16B aligned. e-tile [d][k]: wave reads 4 distinct 32B segs, 16-lane
// broadcast each -> conflict-free.

#define D_     64
#define HW_    1024
#define N_     65536
#define K_     512
#define M_     256     // points per block
#define XPITCH 288     // x row pitch: 8 chunks * 36 (32 used + 4 pad)
#define EPITCH 256     // e-tile row pitch (one 256-code chunk)
#define NDTOT  (N_ * D_)

__global__ __launch_bounds__(512, 2) void vq_fused_kernel(const float* __restrict__ inp,
                                                          const float* __restrict__ emb,
                                                          float* __restrict__ out) {
    __shared__ float ldsx[D_ * XPITCH];  // 73728 B: x-tile [d][chunked p]
    __shared__ float ldse[16896];        // 67584 B: e-tile [64][256] / merge mv+mi overlay
    __shared__ float ldsn[K_];           // ||e_k||^2
    __shared__ float sxs[M_];            // ||x_p||^2
    __shared__ int   fi[M_];             // final index per point
    __shared__ float psum[512];          // loss partials

    const int tid = threadIdx.x;         // 0..511
    const int pg  = tid & 15;            // point-group: 16 points each
    const int kg  = tid >> 4;            // code-group (0..31): 8 codes each
    const int n0  = blockIdx.x * M_;
    const int b   = n0 >> 10;
    const int hw0 = n0 & 1023;
    const float* xbase = inp + b * (D_ * HW_) + hw0;

    // ============ phase A: stage x-tile, ||e||^2, e-chunk0 (all overlapped) ========
    // x: per d, 256 consecutive floats (perfectly coalesced); chunked LDS layout.
#pragma unroll
    for (int i = 0; i < 8; ++i) {
        int q = i * 512 + tid;           // 0..4095 = 64 d * 64 float4-slots
        int d = q >> 6;
        int s = q & 63;                  // float4 slot -> point p = s*4
        float4 v = *(const float4*)(xbase + d * HW_ + s * 4);
        *(float4*)(ldsx + d * XPITCH + (s >> 3) * 36 + (s & 7) * 4) = v;
    }
    // ||e_k||^2: one code per thread, numpy pairwise order.
    {
        const float* e = emb + tid * D_;
        float el[64];
#pragma unroll
        for (int q = 0; q < 16; ++q) {
            float4 v = *(const float4*)(e + q * 4);
            el[4 * q + 0] = v.x; el[4 * q + 1] = v.y;
            el[4 * q + 2] = v.z; el[4 * q + 3] = v.w;
        }
        float r[8];
#pragma unroll
        for (int j = 0; j < 8; ++j) r[j] = __fmul_rn(el[j], el[j]);
#pragma unroll
        for (int i = 1; i < 8; ++i)
#pragma unroll
            for (int j = 0; j < 8; ++j)
                r[j] = __fadd_rn(r[j], __fmul_rn(el[i * 8 + j], el[i * 8 + j]));
        ldsn[tid] = __fadd_rn(__fadd_rn(__fadd_rn(r[0], r[1]), __fadd_rn(r[2], r[3])),
                              __fadd_rn(__fadd_rn(r[4], r[5]), __fadd_rn(r[6], r[7])));
    }
    // e-chunk 0: thread stages code k = tid&255, dim-half dh; transposed to [d][k].
    {
        const int k  = tid & 255;
        const int dh = (tid >> 8) * 32;
        const float* er = emb + k * D_ + dh;
#pragma unroll
        for (int j = 0; j < 8; ++j) {
            float4 v = *(const float4*)(er + j * 4);
            ldse[(dh + j * 4 + 0) * EPITCH + k] = v.x;
            ldse[(dh + j * 4 + 1) * EPITCH + k] = v.y;
            ldse[(dh + j * 4 + 2) * EPITCH + k] = v.z;
            ldse[(dh + j * 4 + 3) * EPITCH + k] = v.w;
        }
    }
    __syncthreads();

    // ---- sxs[p] = ||x_p||^2, numpy pairwise order (threads 0..255) ----
    if (tid < M_) {
        const int colb = (tid >> 5) * 36 + (tid & 31);
        float r[8];
#pragma unroll
        for (int j = 0; j < 8; ++j) {
            float v = ldsx[j * XPITCH + colb];
            r[j] = __fmul_rn(v, v);
        }
#pragma unroll
        for (int i = 1; i < 8; ++i)
#pragma unroll
            for (int j = 0; j < 8; ++j) {
                float v = ldsx[(i * 8 + j) * XPITCH + colb];
                r[j] = __fadd_rn(r[j], __fmul_rn(v, v));
            }
        sxs[tid] = __fadd_rn(__fadd_rn(__fadd_rn(r[0], r[1]), __fadd_rn(r[2], r[3])),
                             __fadd_rn(__fadd_rn(r[4], r[5]), __fadd_rn(r[6], r[7])));
    }
    __syncthreads();

    float runv[16];
    int   runi[16];
#pragma unroll
    for (int j = 0; j < 16; ++j) { runv[j] = 3.4e38f; runi[j] = 0; }

    const float* xcol = ldsx + (pg >> 1) * 36 + (pg & 1) * 16;
    const float* ecol = ldse + kg * 8;

    // ============ main: 2 chunks of 256 codes ======================================
#pragma unroll 1
    for (int c = 0; c < 2; ++c) {
        if (c) {
            __syncthreads();             // chunk-0 inner reads of ldse done
            const int k  = tid & 255;
            const int dh = (tid >> 8) * 32;
            const float* er = emb + (256 + k) * D_ + dh;
#pragma unroll
            for (int j = 0; j < 8; ++j) {
                float4 v = *(const float4*)(er + j * 4);
                ldse[(dh + j * 4 + 0) * EPITCH + k] = v.x;
                ldse[(dh + j * 4 + 1) * EPITCH + k] = v.y;
                ldse[(dh + j * 4 + 2) * EPITCH + k] = v.z;
                ldse[(dh + j * 4 + 3) * EPITCH + k] = v.w;
            }
            __syncthreads();
        }

        float acc[16][8];
#pragma unroll
        for (int j = 0; j < 16; ++j)
#pragma unroll
            for (int q = 0; q < 8; ++q) acc[j][q] = 0.f;

#pragma unroll 2
        for (int d = 0; d < 64; ++d) {
            const float* xr = xcol + d * XPITCH;
            float4 xa = *(const float4*)(xr);
            float4 xb = *(const float4*)(xr + 4);
            float4 xc = *(const float4*)(xr + 8);
            float4 xd = *(const float4*)(xr + 12);
            const float* er = ecol + d * EPITCH;
            float4 ea = *(const float4*)(er);
            float4 eb = *(const float4*)(er + 4);
            float xv[16] = {xa.x, xa.y, xa.z, xa.w, xb.x, xb.y, xb.z, xb.w,
                            xc.x, xc.y, xc.z, xc.w, xd.x, xd.y, xd.z, xd.w};
            float ev[8]  = {ea.x, ea.y, ea.z, ea.w, eb.x, eb.y, eb.z, eb.w};
#pragma unroll
            for (int j = 0; j < 16; ++j)
#pragma unroll
                for (int q = 0; q < 8; ++q)
                    acc[j][q] = fmaf(xv[j], ev[q], acc[j][q]);   // exact d-order chain
        }

        // dist = fp32(fp32(sx + n_k) - 2*dot); strict < keeps first (k ascending)
        const int kidx0 = c * 256 + kg * 8;
        float nk[8];
        {
            float4 na = *(const float4*)(ldsn + kidx0);
            float4 nb = *(const float4*)(ldsn + kidx0 + 4);
            nk[0]=na.x; nk[1]=na.y; nk[2]=na.z; nk[3]=na.w;
            nk[4]=nb.x; nk[5]=nb.y; nk[6]=nb.z; nk[7]=nb.w;
        }
#pragma unroll
        for (int j = 0; j < 16; ++j) {
            const float sx = sxs[pg * 16 + j];   // 4-lane broadcast read
#pragma unroll
            for (int q = 0; q < 8; ++q) {
                float t = __fadd_rn(sx, nk[q]);
                float v = fmaf(-2.0f, acc[j][q], t);   // == fadd(t, -2*acc), exact prod
                if (v < runv[j]) { runv[j] = v; runi[j] = kidx0 + q; }
            }
        }
    }

    // ============ cross-lane argmin merge (32 candidates/point) ====================
    __syncthreads();                     // inner reads of ldse done -> overlay mv/mi
    float* mv = ldse;                    // [256][33] padded
    int*   mi = (int*)(ldse + 256 * 33);
#pragma unroll
    for (int j = 0; j < 16; ++j) {
        int p = pg * 16 + j;
        mv[p * 33 + kg] = runv[j];
        mi[p * 33 + kg] = runi[j];
    }
    __syncthreads();
    if (tid < M_) {
        float bv = 3.4e38f; int bi = 0x7fffffff;
#pragma unroll
        for (int g = 0; g < 32; ++g) {
            float v  = mv[tid * 33 + g];
            int   ii = mi[tid * 33 + g];
            if (v < bv || (v == bv && ii < bi)) { bv = v; bi = ii; }
        }
        fi[tid] = bi;
        out[1 + NDTOT + n0 + tid] = (float)bi;   // idx as float
    }
    __syncthreads();

    // ============ epilogue: quantized NCHW + loss ==================================
    {
        const int p  = tid & 255;        // point
        const int dh = (tid >> 8) * 32;  // dim half
        const float* er2 = emb + fi[p] * D_ + dh;
        float ev2[32];
#pragma unroll
        for (int q = 0; q < 8; ++q) {
            float4 v = *(const float4*)(er2 + 4 * q);
            ev2[4 * q + 0] = v.x; ev2[4 * q + 1] = v.y;
            ev2[4 * q + 2] = v.z; ev2[4 * q + 3] = v.w;
        }
        float* ob = out + 1 + b * (D_ * HW_) + hw0 + p;
        const int colb = (p >> 5) * 36 + (p & 31);
        float local = 0.f;
#pragma unroll
        for (int dd = 0; dd < 32; ++dd) {
            float xv = ldsx[(dh + dd) * XPITCH + colb];
            float df = ev2[dd] - xv;
            local = fmaf(df, df, local);
            ob[(dh + dd) * HW_] = ev2[dd];   // 256 consecutive floats per instr
        }
        psum[tid] = local;
    }
    __syncthreads();
    if (tid < 64) {
        float s = 0.f;
#pragma unroll
        for (int g = 0; g < 8; ++g) s += psum[tid + 64 * g];
#pragma unroll
        for (int off = 32; off > 0; off >>= 1)
            s += __shfl_down(s, off, 64);
        if (tid == 0)
            atomicAdd(out, s * (1.25f / (float)NDTOT));   // loss = 1.25*mean((q-x)^2)
    }
}

extern "C" void kernel_launch(void* const* d_in, const int* in_sizes, int n_in,
                              void* d_out, int out_size, void* d_ws, size_t ws_size,
                              hipStream_t stream) {
    const float* inp = (const float*)d_in[0];
    const float* emb = (const float*)d_in[1];
    float* out = (float*)d_out;
    (void)d_ws; (void)ws_size;

    hipMemsetAsync(d_out, 0, sizeof(float), stream);   // loss accumulator
    vq_fused_kernel<<<256, 512, 0, stream>>>(inp, emb, out);
}